// Round 8
// baseline (4802.959 us; speedup 1.0000x reference)
//
#include <hip/hip_runtime.h>
#include <math.h>

#define B_ 64
#define T_ 2048
#define E_ 128
#define H_ 128
#define G3_ 384   // 3*H
#define C_ 32
#define M_ (T_ * B_)   // 131072 tokens

typedef _Float16 f16x2 __attribute__((ext_vector_type(2)));

__device__ __forceinline__ f16x2 as_h2(unsigned int u) {
    union { unsigned int u; f16x2 h; } c; c.u = u; return c.h;
}

// Single-instruction f16 dot2 with f32 accumulate (guaranteed lowering).
__device__ __forceinline__ float fdot2_acc(f16x2 a, f16x2 b, float c) {
    float d;
    __asm__("v_dot2_f32_f16 %0, %1, %2, %3" : "=v"(d) : "v"(a), "v"(b), "v"(c));
    return d;
}

// lgkm-only barrier: all cross-thread data is in LDS; global loads/stores
// stay in flight across it, letting the compiler's precise per-register
// vmcnt(N) waits exclude unrelated stores (see gru loop ordering).
__device__ __forceinline__ void lds_barrier() {
    __asm__ volatile("s_waitcnt lgkmcnt(0)\n\ts_barrier" ::: "memory");
}

// ---------------------------------------------------------------------------
// K1/K3: gi[m][g] = bias[g] + dot(w[g][:], row_m[:]) ; m = t*B + b
// (r7 version, unchanged)
// ---------------------------------------------------------------------------
template <bool GATHER>
__global__ __launch_bounds__(128, 1) void gates_gemm(
    const float* __restrict__ src,
    const int*   __restrict__ xidx,
    const float* __restrict__ w,
    const float* __restrict__ bias,
    float* __restrict__ gi)
{
    const int g = threadIdx.x;  // 0..127
    f16x2 wr[3][64];
#pragma unroll
    for (int r = 0; r < 3; r++) {
        const float2* w2 = (const float2*)(w + (g + 128 * r) * 128);
#pragma unroll
        for (int i = 0; i < 64; i++) {
            float2 v = w2[i];
            wr[r][i] = (f16x2){(_Float16)v.x, (_Float16)v.y};
        }
    }
    const float bg0 = bias[g], bg1 = bias[g + 128], bg2 = bias[g + 256];

    __shared__ __align__(16) f16x2 rows[8][64];

    for (int grp = blockIdx.x; grp < M_ / 8; grp += gridDim.x) {
        const int m0 = grp * 8;
        lds_barrier();
#pragma unroll
        for (int k = 0; k < 4; k++) {
            const int j = g + 128 * k;
            const int s = j >> 6;
            const int p = j & 63;
            const int mm = m0 + s;
            long row;
            if (GATHER) {
                const int t = mm >> 6;
                const int b = mm & 63;
                row = (long)xidx[b * T_ + t];
            } else {
                row = mm;
            }
            float2 v = ((const float2*)(src + row * 128))[p];
            rows[s][p] = (f16x2){(_Float16)v.x, (_Float16)v.y};
        }
        lds_barrier();
        for (int s = 0; s < 8; s++) {
            const uint4* h16 = (const uint4*)rows[s];
            float a00 = bg0, a01 = 0.f, a10 = bg1, a11 = 0.f, a20 = bg2, a21 = 0.f;
#pragma unroll
            for (int i = 0; i < 16; i++) {
                uint4 u = h16[i];
                f16x2 ux = as_h2(u.x), uy = as_h2(u.y), uz = as_h2(u.z), uw = as_h2(u.w);
                a00 = fdot2_acc(wr[0][4*i+0], ux, a00);
                a10 = fdot2_acc(wr[1][4*i+0], ux, a10);
                a20 = fdot2_acc(wr[2][4*i+0], ux, a20);
                a01 = fdot2_acc(wr[0][4*i+1], uy, a01);
                a11 = fdot2_acc(wr[1][4*i+1], uy, a11);
                a21 = fdot2_acc(wr[2][4*i+1], uy, a21);
                a00 = fdot2_acc(wr[0][4*i+2], uz, a00);
                a10 = fdot2_acc(wr[1][4*i+2], uz, a10);
                a20 = fdot2_acc(wr[2][4*i+2], uz, a20);
                a01 = fdot2_acc(wr[0][4*i+3], uw, a01);
                a11 = fdot2_acc(wr[1][4*i+3], uw, a11);
                a21 = fdot2_acc(wr[2][4*i+3], uw, a21);
            }
            float* go = gi + (long)(m0 + s) * G3_ + g;
            go[0]   = a00 + a01;
            go[128] = a10 + a11;
            go[256] = a20 + a21;
        }
    }
}

// ---------------------------------------------------------------------------
// K2/K4: GRU recurrence, T=192 / r=2 rebalance.
// Evidence (r4-r7): at T=128 the step is pinned ~1600 cyc regardless of LDS
// or barrier structure -> dot-issue-bound (v_dot2 ~4cyc/instr). T=192
// balances per-wave dot issue (128 dot2) against LDS broadcast (48 b128/CU).
// Thread g<192 owns w_hh rows {g, g+192} (128 f16x2 VGPRs); gh exchanged
// via LDS; gate math on threads g<128. y-store issued AFTER next step's gi
// loads (value carried in a register) so precise vmcnt excludes the store
// and gi gets a full-iteration prefetch cover; lgkm-only barriers keep all
// of it in flight.
// ---------------------------------------------------------------------------
__global__ __launch_bounds__(192, 1) void gru_layer(
    const float* __restrict__ gi,    // [M,384]
    const float* __restrict__ w_hh,  // [384,128]
    const float* __restrict__ b_hh,  // [384]
    float* __restrict__ y)           // [M,128]
{
    const int g = threadIdx.x;  // 0..191
    const int b = blockIdx.x;

    f16x2 wr0[64], wr1[64];
    {
        const float2* w2a = (const float2*)(w_hh + g * 128);
        const float2* w2b = (const float2*)(w_hh + (g + 192) * 128);
#pragma unroll
        for (int i = 0; i < 64; i++) {
            float2 va = w2a[i], vb = w2b[i];
            wr0[i] = (f16x2){(_Float16)va.x, (_Float16)va.y};
            wr1[i] = (f16x2){(_Float16)vb.x, (_Float16)vb.y};
        }
    }
    const float bg0 = b_hh[g];
    const float bg1 = b_hh[g + 192];

    __shared__ __align__(16) f16x2 hb[2][64];   // double-buffered h (f16)
    __shared__ float gh_lds[384];

    float h_own = 0.f;
    if (g < 64) hb[0][g] = (f16x2){(_Float16)0.f, (_Float16)0.f};
    __syncthreads();

    const float* gi_b = gi + (long)b * G3_;
    float* y_b = y + (long)b * H_;
    const bool gate_th = (g < 128);   // wave-uniform (waves 0,1 vs wave 2)

    // preload gi(0)
    float ir = 0.f, iz = 0.f, inn = 0.f;
    if (gate_th) { ir = gi_b[g]; iz = gi_b[128 + g]; inn = gi_b[256 + g]; }
    float y_prev = 0.f;

    for (int t = 0; t < T_; t++) {
        // (1) prefetch gi(t+1)  — oldest vmem of this iteration
        float ir_n = 0.f, iz_n = 0.f, inn_n = 0.f;
        if (gate_th && t + 1 < T_) {
            const float* gi_n = gi_b + (long)(t + 1) * (B_ * G3_);
            ir_n = gi_n[g]; iz_n = gi_n[128 + g]; inn_n = gi_n[256 + g];
        }
        // (2) y-store of PREVIOUS step — issued after the loads above, so
        // waits for gi never include the store-ack
        if (gate_th && t > 0) {
            y_b[(long)(t - 1) * (B_ * H_) + g] = y_prev;
        }

        // (3) hh-dot: 2 rows x 64 dot2, 8 accumulator chains
        const uint4* h16 = (const uint4*)hb[t & 1];
        float p00 = bg0, p01 = 0.f, p02 = 0.f, p03 = 0.f;
        float p10 = bg1, p11 = 0.f, p12 = 0.f, p13 = 0.f;
#pragma unroll
        for (int i = 0; i < 16; i++) {
            uint4 u = h16[i];
            f16x2 ux = as_h2(u.x), uy = as_h2(u.y), uz = as_h2(u.z), uw = as_h2(u.w);
            p00 = fdot2_acc(wr0[4*i+0], ux, p00);
            p10 = fdot2_acc(wr1[4*i+0], ux, p10);
            p01 = fdot2_acc(wr0[4*i+1], uy, p01);
            p11 = fdot2_acc(wr1[4*i+1], uy, p11);
            p02 = fdot2_acc(wr0[4*i+2], uz, p02);
            p12 = fdot2_acc(wr1[4*i+2], uz, p12);
            p03 = fdot2_acc(wr0[4*i+3], uw, p03);
            p13 = fdot2_acc(wr1[4*i+3], uw, p13);
        }
        gh_lds[g]       = (p00 + p01) + (p02 + p03);
        gh_lds[g + 192] = (p10 + p11) + (p12 + p13);
        lds_barrier();   // gh visible

        // (4) gate phase on threads 0..127
        if (gate_th) {
            const float hr = gh_lds[g];
            const float hz = gh_lds[128 + g];
            const float hn = gh_lds[256 + g];
            const float r = 1.f / (1.f + __expf(-(ir + hr)));
            const float z = 1.f / (1.f + __expf(-(iz + hz)));
            const float narg = inn + r * hn;
            const float n = 1.f - 2.f / (__expf(2.f * narg) + 1.f);  // tanh
            h_own = (1.f - z) * n + z * h_own;
            ((_Float16*)hb[(t + 1) & 1])[g] = (_Float16)h_own;
            y_prev = h_own;
        }
        lds_barrier();   // h(t+1) visible for next dot

        ir = ir_n; iz = iz_n; inn = inn_n;
    }
    // tail store
    if (gate_th) y_b[(long)(T_ - 1) * (B_ * H_) + g] = y_prev;
}

// ---------------------------------------------------------------------------
// K5: out[b*T+t][c] = relu(fc_b[c] + dot(fc_w[c], y[t*B+b]))
// ---------------------------------------------------------------------------
__global__ __launch_bounds__(256, 2) void fc_relu(
    const float* __restrict__ y,
    const float* __restrict__ fc_w,
    const float* __restrict__ fc_b,
    float* __restrict__ out)
{
    const int tid = threadIdx.x;
    const int c = tid & 31;
    const int slot = tid >> 5;

    float4 wr[32];
    const float4* w4 = (const float4*)(fc_w + c * 128);
#pragma unroll
    for (int i = 0; i < 32; i++) wr[i] = w4[i];
    const float bc = fc_b[c];

    __shared__ __align__(16) float rows[8][128];

    for (int grp = blockIdx.x; grp < M_ / 8; grp += gridDim.x) {
        const int m0 = grp * 8;
        lds_barrier();
        for (int i = tid; i < 8 * 128; i += 256) {
            rows[i >> 7][i & 127] = y[(long)m0 * 128 + i];
        }
        lds_barrier();
        const float4* h4 = (const float4*)rows[slot];
        float a0 = bc, a1 = 0.f, a2 = 0.f, a3 = 0.f;
#pragma unroll
        for (int i = 0; i < 32; i += 4) {
            float4 h0 = h4[i], h1 = h4[i + 1], h2 = h4[i + 2], h3 = h4[i + 3];
            a0 = fmaf(wr[i].w, h0.w, fmaf(wr[i].z, h0.z, fmaf(wr[i].y, h0.y, fmaf(wr[i].x, h0.x, a0))));
            a1 = fmaf(wr[i+1].w, h1.w, fmaf(wr[i+1].z, h1.z, fmaf(wr[i+1].y, h1.y, fmaf(wr[i+1].x, h1.x, a1))));
            a2 = fmaf(wr[i+2].w, h2.w, fmaf(wr[i+2].z, h2.z, fmaf(wr[i+2].y, h2.y, fmaf(wr[i+2].x, h2.x, a2))));
            a3 = fmaf(wr[i+3].w, h3.w, fmaf(wr[i+3].z, h3.z, fmaf(wr[i+3].y, h3.y, fmaf(wr[i+3].x, h3.x, a3))));
        }
        float acc = (a0 + a1) + (a2 + a3);
        acc = fmaxf(acc, 0.f);
        const int m = m0 + slot;
        const int t = m >> 6;
        const int b = m & 63;
        out[((long)b * T_ + t) * C_ + c] = acc;
    }
}

// ---------------------------------------------------------------------------
extern "C" void kernel_launch(void* const* d_in, const int* in_sizes, int n_in,
                              void* d_out, int out_size, void* d_ws, size_t ws_size,
                              hipStream_t stream) {
    const int*   x     = (const int*)d_in[0];
    const float* emb   = (const float*)d_in[1];
    const float* w_ih0 = (const float*)d_in[2];
    const float* w_hh0 = (const float*)d_in[3];
    const float* b_ih0 = (const float*)d_in[4];
    const float* b_hh0 = (const float*)d_in[5];
    const float* w_ih1 = (const float*)d_in[6];
    const float* w_hh1 = (const float*)d_in[7];
    const float* b_ih1 = (const float*)d_in[8];
    const float* b_hh1 = (const float*)d_in[9];
    const float* fc_w  = (const float*)d_in[10];
    const float* fc_b  = (const float*)d_in[11];
    float* out = (float*)d_out;

    float* gi = (float*)d_ws;
    float* yb = (float*)((char*)d_ws + (size_t)M_ * G3_ * sizeof(float));

    gates_gemm<true><<<512, 128, 0, stream>>>(emb, x, w_ih0, b_ih0, gi);
    gru_layer<<<B_, 192, 0, stream>>>(gi, w_hh0, b_hh0, yb);
    gates_gemm<false><<<512, 128, 0, stream>>>(yb, nullptr, w_ih1, b_ih1, gi);
    gru_layer<<<B_, 192, 0, stream>>>(gi, w_hh1, b_hh1, yb);
    fc_relu<<<512, 256, 0, stream>>>(yb, fc_w, fc_b, out);
}

// Round 9
// 3441.171 us; speedup vs baseline: 1.3957x; 1.3957x over previous
//
#include <hip/hip_runtime.h>
#include <math.h>

#define B_ 64
#define T_ 2048
#define E_ 128
#define H_ 128
#define G3_ 384   // 3*H
#define C_ 32
#define M_ (T_ * B_)   // 131072 tokens

typedef _Float16 f16x2 __attribute__((ext_vector_type(2)));

__device__ __forceinline__ f16x2 as_h2(unsigned int u) {
    union { unsigned int u; f16x2 h; } c; c.u = u; return c.h;
}

// Single-instruction f16 dot2 with f32 accumulate (guaranteed lowering).
__device__ __forceinline__ float fdot2_acc(f16x2 a, f16x2 b, float c) {
    float d;
    __asm__("v_dot2_f32_f16 %0, %1, %2, %3" : "=v"(d) : "v"(a), "v"(b), "v"(c));
    return d;
}

// lgkm-only barrier for the gru step loop (cross-thread data is LDS-only;
// keeps y-store acks / gi loads in flight). NOT used in gates/fc — measured
// +200us regression there (r5->r6), likely store-queue backpressure.
__device__ __forceinline__ void lds_barrier() {
    __asm__ volatile("s_waitcnt lgkmcnt(0)\n\ts_barrier" ::: "memory");
}

// ---------------------------------------------------------------------------
// K1/K3: gi[m][g] = bias[g] + dot(w[g][:], row_m[:]) ; m = t*B + b
// r=3 f16 weight-stationary, __syncthreads barriers (measured best, r4).
// ---------------------------------------------------------------------------
template <bool GATHER>
__global__ __launch_bounds__(128, 1) void gates_gemm(
    const float* __restrict__ src,
    const int*   __restrict__ xidx,
    const float* __restrict__ w,
    const float* __restrict__ bias,
    float* __restrict__ gi)
{
    const int g = threadIdx.x;  // 0..127
    f16x2 wr[3][64];
#pragma unroll
    for (int r = 0; r < 3; r++) {
        const float2* w2 = (const float2*)(w + (g + 128 * r) * 128);
#pragma unroll
        for (int i = 0; i < 64; i++) {
            float2 v = w2[i];
            wr[r][i] = (f16x2){(_Float16)v.x, (_Float16)v.y};
        }
    }
    const float bg0 = bias[g], bg1 = bias[g + 128], bg2 = bias[g + 256];

    __shared__ __align__(16) f16x2 rows[8][64];

    for (int grp = blockIdx.x; grp < M_ / 8; grp += gridDim.x) {
        const int m0 = grp * 8;
        __syncthreads();
#pragma unroll
        for (int k = 0; k < 4; k++) {
            const int j = g + 128 * k;
            const int s = j >> 6;
            const int p = j & 63;
            const int mm = m0 + s;
            long row;
            if (GATHER) {
                const int t = mm >> 6;
                const int b = mm & 63;
                row = (long)xidx[b * T_ + t];
            } else {
                row = mm;
            }
            float2 v = ((const float2*)(src + row * 128))[p];
            rows[s][p] = (f16x2){(_Float16)v.x, (_Float16)v.y};
        }
        __syncthreads();
        for (int s = 0; s < 8; s++) {
            const uint4* h16 = (const uint4*)rows[s];
            float a00 = bg0, a01 = 0.f, a10 = bg1, a11 = 0.f, a20 = bg2, a21 = 0.f;
#pragma unroll
            for (int i = 0; i < 16; i++) {
                uint4 u = h16[i];
                f16x2 ux = as_h2(u.x), uy = as_h2(u.y), uz = as_h2(u.z), uw = as_h2(u.w);
                a00 = fdot2_acc(wr[0][4*i+0], ux, a00);
                a10 = fdot2_acc(wr[1][4*i+0], ux, a10);
                a20 = fdot2_acc(wr[2][4*i+0], ux, a20);
                a01 = fdot2_acc(wr[0][4*i+1], uy, a01);
                a11 = fdot2_acc(wr[1][4*i+1], uy, a11);
                a21 = fdot2_acc(wr[2][4*i+1], uy, a21);
                a00 = fdot2_acc(wr[0][4*i+2], uz, a00);
                a10 = fdot2_acc(wr[1][4*i+2], uz, a10);
                a20 = fdot2_acc(wr[2][4*i+2], uz, a20);
                a01 = fdot2_acc(wr[0][4*i+3], uw, a01);
                a11 = fdot2_acc(wr[1][4*i+3], uw, a11);
                a21 = fdot2_acc(wr[2][4*i+3], uw, a21);
            }
            float* go = gi + (long)(m0 + s) * G3_ + g;
            go[0]   = a00 + a01;
            go[128] = a10 + a11;
            go[256] = a20 + a21;
        }
    }
}

// ---------------------------------------------------------------------------
// K2/K4: GRU recurrence. T=128, r=3, in-thread gates, 1 lgkm-barrier/step
// (r7 structure) + NEW: h-tile HOISTED into a 16-uint4 register buffer.
// Theory (r8 falsified issue-bound): with 192 weight VGPRs and ~8 spare,
// the compiler serialized ds_read->dot2 pairs, exposing ~100cyc LDS latency
// 16x per step. 64 extra VGPRs of h-buffer let all 16 b128 reads pipeline
// (~300cyc total), then the dot runs from registers.
// ---------------------------------------------------------------------------
__global__ __launch_bounds__(128, 1) void gru_layer(
    const float* __restrict__ gi,    // [M,384]
    const float* __restrict__ w_hh,  // [384,128]
    const float* __restrict__ b_hh,  // [384]
    float* __restrict__ y)           // [M,128]
{
    const int g = threadIdx.x;  // h-dim 0..127
    const int b = blockIdx.x;

    f16x2 wr[3][64];
#pragma unroll
    for (int r = 0; r < 3; r++) {
        const float2* w2 = (const float2*)(w_hh + (g + 128 * r) * 128);
#pragma unroll
        for (int i = 0; i < 64; i++) {
            float2 v = w2[i];
            wr[r][i] = (f16x2){(_Float16)v.x, (_Float16)v.y};
        }
    }
    const float bg0 = b_hh[g], bg1 = b_hh[g + 128], bg2 = b_hh[g + 256];

    __shared__ __align__(16) f16x2 hb[2][64];   // double-buffered h (f16)

    float h_own = 0.f;
    if (g < 64) hb[0][g] = (f16x2){(_Float16)0.f, (_Float16)0.f};
    __syncthreads();

    const float* gi_b = gi + (long)b * G3_;
    float* y_b = y + (long)b * H_;

    for (int t = 0; t < T_; t++) {
        const float* gi_t = gi_b + (long)t * (B_ * G3_);
        const float ir = gi_t[g];
        const float iz = gi_t[128 + g];
        const float inn = gi_t[256 + g];

        // ---- hoist all of h into registers: 16 pipelined ds_read_b128 ----
        const uint4* h16 = (const uint4*)hb[t & 1];
        uint4 hreg[16];
#pragma unroll
        for (int i = 0; i < 16; i++) hreg[i] = h16[i];

        float a00 = bg0, a01 = 0.f, a10 = bg1, a11 = 0.f, a20 = bg2, a21 = 0.f;
#pragma unroll
        for (int i = 0; i < 16; i++) {
            uint4 u = hreg[i];
            f16x2 ux = as_h2(u.x), uy = as_h2(u.y), uz = as_h2(u.z), uw = as_h2(u.w);
            a00 = fdot2_acc(wr[0][4*i+0], ux, a00);
            a10 = fdot2_acc(wr[1][4*i+0], ux, a10);
            a20 = fdot2_acc(wr[2][4*i+0], ux, a20);
            a01 = fdot2_acc(wr[0][4*i+1], uy, a01);
            a11 = fdot2_acc(wr[1][4*i+1], uy, a11);
            a21 = fdot2_acc(wr[2][4*i+1], uy, a21);
            a00 = fdot2_acc(wr[0][4*i+2], uz, a00);
            a10 = fdot2_acc(wr[1][4*i+2], uz, a10);
            a20 = fdot2_acc(wr[2][4*i+2], uz, a20);
            a01 = fdot2_acc(wr[0][4*i+3], uw, a01);
            a11 = fdot2_acc(wr[1][4*i+3], uw, a11);
            a21 = fdot2_acc(wr[2][4*i+3], uw, a21);
        }
        const float hr = a00 + a01;
        const float hz = a10 + a11;
        const float hn = a20 + a21;

        const float r = 1.f / (1.f + __expf(-(ir + hr)));
        const float z = 1.f / (1.f + __expf(-(iz + hz)));
        const float narg = inn + r * hn;
        const float n = 1.f - 2.f / (__expf(2.f * narg) + 1.f);  // tanh
        h_own = (1.f - z) * n + z * h_own;

        ((_Float16*)hb[(t + 1) & 1])[g] = (_Float16)h_own;  // write OTHER buffer
        y_b[(long)t * (B_ * H_) + g] = h_own;
        lds_barrier();     // LDS writes visible; vmem stays in flight
    }
}

// ---------------------------------------------------------------------------
// K5: out[b*T+t][c] = relu(fc_b[c] + dot(fc_w[c], y[t*B+b]))
// ---------------------------------------------------------------------------
__global__ __launch_bounds__(256, 2) void fc_relu(
    const float* __restrict__ y,
    const float* __restrict__ fc_w,
    const float* __restrict__ fc_b,
    float* __restrict__ out)
{
    const int tid = threadIdx.x;
    const int c = tid & 31;
    const int slot = tid >> 5;

    float4 wr[32];
    const float4* w4 = (const float4*)(fc_w + c * 128);
#pragma unroll
    for (int i = 0; i < 32; i++) wr[i] = w4[i];
    const float bc = fc_b[c];

    __shared__ __align__(16) float rows[8][128];

    for (int grp = blockIdx.x; grp < M_ / 8; grp += gridDim.x) {
        const int m0 = grp * 8;
        __syncthreads();
        for (int i = tid; i < 8 * 128; i += 256) {
            rows[i >> 7][i & 127] = y[(long)m0 * 128 + i];
        }
        __syncthreads();
        const float4* h4 = (const float4*)rows[slot];
        float a0 = bc, a1 = 0.f, a2 = 0.f, a3 = 0.f;
#pragma unroll
        for (int i = 0; i < 32; i += 4) {
            float4 h0 = h4[i], h1 = h4[i + 1], h2 = h4[i + 2], h3 = h4[i + 3];
            a0 = fmaf(wr[i].w, h0.w, fmaf(wr[i].z, h0.z, fmaf(wr[i].y, h0.y, fmaf(wr[i].x, h0.x, a0))));
            a1 = fmaf(wr[i+1].w, h1.w, fmaf(wr[i+1].z, h1.z, fmaf(wr[i+1].y, h1.y, fmaf(wr[i+1].x, h1.x, a1))));
            a2 = fmaf(wr[i+2].w, h2.w, fmaf(wr[i+2].z, h2.z, fmaf(wr[i+2].y, h2.y, fmaf(wr[i+2].x, h2.x, a2))));
            a3 = fmaf(wr[i+3].w, h3.w, fmaf(wr[i+3].z, h3.z, fmaf(wr[i+3].y, h3.y, fmaf(wr[i+3].x, h3.x, a3))));
        }
        float acc = (a0 + a1) + (a2 + a3);
        acc = fmaxf(acc, 0.f);
        const int m = m0 + slot;
        const int t = m >> 6;
        const int b = m & 63;
        out[((long)b * T_ + t) * C_ + c] = acc;
    }
}

// ---------------------------------------------------------------------------
extern "C" void kernel_launch(void* const* d_in, const int* in_sizes, int n_in,
                              void* d_out, int out_size, void* d_ws, size_t ws_size,
                              hipStream_t stream) {
    const int*   x     = (const int*)d_in[0];
    const float* emb   = (const float*)d_in[1];
    const float* w_ih0 = (const float*)d_in[2];
    const float* w_hh0 = (const float*)d_in[3];
    const float* b_ih0 = (const float*)d_in[4];
    const float* b_hh0 = (const float*)d_in[5];
    const float* w_ih1 = (const float*)d_in[6];
    const float* w_hh1 = (const float*)d_in[7];
    const float* b_ih1 = (const float*)d_in[8];
    const float* b_hh1 = (const float*)d_in[9];
    const float* fc_w  = (const float*)d_in[10];
    const float* fc_b  = (const float*)d_in[11];
    float* out = (float*)d_out;

    float* gi = (float*)d_ws;
    float* yb = (float*)((char*)d_ws + (size_t)M_ * G3_ * sizeof(float));

    gates_gemm<true><<<512, 128, 0, stream>>>(emb, x, w_ih0, b_ih0, gi);
    gru_layer<<<B_, 128, 0, stream>>>(gi, w_hh0, b_hh0, yb);
    gates_gemm<false><<<512, 128, 0, stream>>>(yb, nullptr, w_ih1, b_ih1, gi);
    gru_layer<<<B_, 128, 0, stream>>>(gi, w_hh1, b_hh1, yb);
    fc_relu<<<512, 256, 0, stream>>>(yb, fc_w, fc_b, out);
}